// Round 1
// baseline (356.337 us; speedup 1.0000x reference)
//
#include <hip/hip_runtime.h>
#include <math.h>

// Problem constants (reference: N=8192, M=8192, D=64, fp32)
#define NN 8192
#define MM 8192
#define DD 64
#define BM 128
#define BN 128
#define LDS_S 132  // padded stride for [k][m] tiles: writes 2-way-free-ish, reads conflict-free

__device__ __forceinline__ float softplus_f(float x) {
    // logaddexp(x, 0) = max(x,0) + log1p(exp(-|x|)), fp32-stable
    return fmaxf(x, 0.0f) + log1pf(exp2f(-fabsf(x) * 1.4426950408889634f));
}

__global__ __launch_bounds__(256, 2)
void rbf_tile_kernel(const float* __restrict__ X, const float* __restrict__ X2,
                     const float* __restrict__ raw_l, const float* __restrict__ raw_v,
                     float* __restrict__ out) {
    // [k][m] layout so the hot loop reads contiguous float4 along m (conflict-free b128)
    __shared__ float As[DD][LDS_S];
    __shared__ float Bs[DD][LDS_S];
    __shared__ float xn[BM];
    __shared__ float yn[BN];

    const int t  = threadIdx.x;
    const int bn = blockIdx.x;  // M tiles (fast-varying for store locality)
    const int bm = blockIdx.y;  // N tiles

    // ---- stage both tiles (whole K fits: load once, no K loop) ----
    const int k4 = t & 15;   // which float4 along D
    const int r0 = t >> 4;   // base row 0..15

    // inverse lengthscales for this thread's k-slice (softplus folded here)
    float4 rl = ((const float4*)raw_l)[k4];
    const float il0 = 1.0f / softplus_f(rl.x);
    const float il1 = 1.0f / softplus_f(rl.y);
    const float il2 = 1.0f / softplus_f(rl.z);
    const float il3 = 1.0f / softplus_f(rl.w);

    const float* Xb  = X  + (size_t)(bm * BM) * DD;
    const float* X2b = X2 + (size_t)(bn * BN) * DD;

#pragma unroll
    for (int r = 0; r < 8; ++r) {
        const int row = r0 + 16 * r;  // 0..127
        float4 a = *(const float4*)(Xb + row * DD + 4 * k4);
        As[4 * k4 + 0][row] = a.x * il0;
        As[4 * k4 + 1][row] = a.y * il1;
        As[4 * k4 + 2][row] = a.z * il2;
        As[4 * k4 + 3][row] = a.w * il3;
        float4 b = *(const float4*)(X2b + row * DD + 4 * k4);
        Bs[4 * k4 + 0][row] = b.x * il0;
        Bs[4 * k4 + 1][row] = b.y * il1;
        Bs[4 * k4 + 2][row] = b.z * il2;
        Bs[4 * k4 + 3][row] = b.w * il3;
    }
    __syncthreads();

    // ---- row norms (wave-uniform split: waves 0-1 -> xn, waves 2-3 -> yn) ----
    {
        const int c = t & 127;
        float s = 0.0f;
        if (t < 128) {
#pragma unroll
            for (int k = 0; k < DD; ++k) { float a = As[k][c]; s = fmaf(a, a, s); }
            xn[c] = s;
        } else {
#pragma unroll
            for (int k = 0; k < DD; ++k) { float b = Bs[k][c]; s = fmaf(b, b, s); }
            yn[c] = s;
        }
    }
    __syncthreads();

    // ---- 8x8 micro-tile GEMM (cross = Xl . X2l^T) ----
    const int tx = t & 15;
    const int ty = t >> 4;

    float acc[2][4][2][4];  // [ii][i][jj][j]
#pragma unroll
    for (int ii = 0; ii < 2; ++ii)
#pragma unroll
        for (int i = 0; i < 4; ++i)
#pragma unroll
            for (int jj = 0; jj < 2; ++jj)
#pragma unroll
                for (int j = 0; j < 4; ++j) acc[ii][i][jj][j] = 0.0f;

#pragma unroll 4
    for (int k = 0; k < DD; ++k) {
        float4 a0 = *(const float4*)&As[k][4 * ty];
        float4 a1 = *(const float4*)&As[k][4 * ty + 64];
        float4 b0 = *(const float4*)&Bs[k][4 * tx];
        float4 b1 = *(const float4*)&Bs[k][4 * tx + 64];
        float a[2][4] = {{a0.x, a0.y, a0.z, a0.w}, {a1.x, a1.y, a1.z, a1.w}};
        float b[2][4] = {{b0.x, b0.y, b0.z, b0.w}, {b1.x, b1.y, b1.z, b1.w}};
#pragma unroll
        for (int ii = 0; ii < 2; ++ii)
#pragma unroll
            for (int i = 0; i < 4; ++i)
#pragma unroll
                for (int jj = 0; jj < 2; ++jj)
#pragma unroll
                    for (int j = 0; j < 4; ++j)
                        acc[ii][i][jj][j] = fmaf(a[ii][i], b[jj][j], acc[ii][i][jj][j]);
    }

    // ---- epilogue: d2 = max(xn+yn-2*cross, 0); out = v * exp(-0.5*d2) ----
    const float v = softplus_f(raw_v[0]);
    const float c_exp = -0.5f * 1.4426950408889634f;  // exp(-0.5*d2) = exp2(c_exp*d2)

#pragma unroll
    for (int ii = 0; ii < 2; ++ii) {
#pragma unroll
        for (int i = 0; i < 4; ++i) {
            const int m = 4 * ty + 64 * ii + i;
            const float xnm = xn[m];
            float* orow = out + (size_t)(bm * BM + m) * MM + bn * BN;
#pragma unroll
            for (int jj = 0; jj < 2; ++jj) {
                const int n0 = 4 * tx + 64 * jj;
                float4 o;
                {
                    float d2 = fmaxf(xnm + yn[n0 + 0] - 2.0f * acc[ii][i][jj][0], 0.0f);
                    o.x = v * exp2f(c_exp * d2);
                }
                {
                    float d2 = fmaxf(xnm + yn[n0 + 1] - 2.0f * acc[ii][i][jj][1], 0.0f);
                    o.y = v * exp2f(c_exp * d2);
                }
                {
                    float d2 = fmaxf(xnm + yn[n0 + 2] - 2.0f * acc[ii][i][jj][2], 0.0f);
                    o.z = v * exp2f(c_exp * d2);
                }
                {
                    float d2 = fmaxf(xnm + yn[n0 + 3] - 2.0f * acc[ii][i][jj][3], 0.0f);
                    o.w = v * exp2f(c_exp * d2);
                }
                *(float4*)(orow + n0) = o;
            }
        }
    }
}

extern "C" void kernel_launch(void* const* d_in, const int* in_sizes, int n_in,
                              void* d_out, int out_size, void* d_ws, size_t ws_size,
                              hipStream_t stream) {
    const float* X     = (const float*)d_in[0];
    const float* X2    = (const float*)d_in[1];
    const float* raw_l = (const float*)d_in[2];
    const float* raw_v = (const float*)d_in[3];
    float* out = (float*)d_out;

    dim3 grid(MM / BN, NN / BM);  // (64, 64)
    dim3 block(256);
    rbf_tile_kernel<<<grid, block, 0, stream>>>(X, X2, raw_l, raw_v, out);
}

// Round 2
// 325.677 us; speedup vs baseline: 1.0941x; 1.0941x over previous
//
#include <hip/hip_runtime.h>
#include <math.h>

// RBF kernel: N=M=8192, D=64, fp32 in/out.
// Strategy: cross-term GEMM via split-bf16 MFMA (hi+lo decomposition, 3 GEMMs,
// fp32 accumulate). Error in d2 ~1e-3 vs 0.04 budget (threshold = 2% of
// absmax(ref)=8.7e-10; min d2 ~ 42). Norms in exact fp32. Write-bound target
// ~41 us (256 MB out @ 6.3 TB/s).
#define NN 8192
#define MM 8192
#define DD 64
#define BM 128
#define BN 128
#define STR 72  // bf16 row stride (64+8 pad): frag-read banks become 2-way (free)

typedef __bf16 bf16x8 __attribute__((ext_vector_type(8)));
typedef __bf16 bf16x4 __attribute__((ext_vector_type(4)));
typedef float f32x4 __attribute__((ext_vector_type(4)));

__device__ __forceinline__ float softplus_f(float x) {
    // logaddexp(x, 0) = max(x,0) + log1p(exp(-|x|)), fp32-stable
    return fmaxf(x, 0.0f) + log1pf(exp2f(-fabsf(x) * 1.4426950408889634f));
}

__global__ __launch_bounds__(256, 2)
void rbf_mfma_kernel(const float* __restrict__ X, const float* __restrict__ X2,
                     const float* __restrict__ raw_l, const float* __restrict__ raw_v,
                     float* __restrict__ out) {
    __shared__ __bf16 Ah[BM][STR];
    __shared__ __bf16 Al[BM][STR];
    __shared__ __bf16 Bh[BN][STR];
    __shared__ __bf16 Bl[BN][STR];
    __shared__ float ls[DD];   // 1/softplus(raw_l)
    __shared__ float xn[BM];
    __shared__ float yn[BN];

    const int t  = threadIdx.x;
    const int bn = blockIdx.x;
    const int bm = blockIdx.y;

    if (t < DD) ls[t] = 1.0f / softplus_f(raw_l[t]);
    __syncthreads();

    // ---- stage: load fp32, scale, split into bf16 hi/lo, write LDS ----
    const int k4 = t & 15;   // float4 index along D
    const int r0 = t >> 4;
    const float il0 = ls[4 * k4 + 0];
    const float il1 = ls[4 * k4 + 1];
    const float il2 = ls[4 * k4 + 2];
    const float il3 = ls[4 * k4 + 3];

    const float* Xb  = X  + (size_t)(bm * BM) * DD;
    const float* X2b = X2 + (size_t)(bn * BN) * DD;

#pragma unroll
    for (int r = 0; r < 8; ++r) {
        const int row = r0 + 16 * r;
        {
            float4 a = *(const float4*)(Xb + row * DD + 4 * k4);
            a.x *= il0; a.y *= il1; a.z *= il2; a.w *= il3;
            bf16x4 h, l;
            h[0] = (__bf16)a.x; l[0] = (__bf16)(a.x - (float)h[0]);
            h[1] = (__bf16)a.y; l[1] = (__bf16)(a.y - (float)h[1]);
            h[2] = (__bf16)a.z; l[2] = (__bf16)(a.z - (float)h[2]);
            h[3] = (__bf16)a.w; l[3] = (__bf16)(a.w - (float)h[3]);
            *(bf16x4*)&Ah[row][4 * k4] = h;
            *(bf16x4*)&Al[row][4 * k4] = l;
        }
        {
            float4 b = *(const float4*)(X2b + row * DD + 4 * k4);
            b.x *= il0; b.y *= il1; b.z *= il2; b.w *= il3;
            bf16x4 h, l;
            h[0] = (__bf16)b.x; l[0] = (__bf16)(b.x - (float)h[0]);
            h[1] = (__bf16)b.y; l[1] = (__bf16)(b.y - (float)h[1]);
            h[2] = (__bf16)b.z; l[2] = (__bf16)(b.z - (float)h[2]);
            h[3] = (__bf16)b.w; l[3] = (__bf16)(b.w - (float)h[3]);
            *(bf16x4*)&Bh[row][4 * k4] = h;
            *(bf16x4*)&Bl[row][4 * k4] = l;
        }
    }

    // ---- exact fp32 row norms, straight from global (L1/L2-hot) ----
    {
        const int rowl = t & 127;
        const float* p = (t < 128) ? (Xb + rowl * DD) : (X2b + rowl * DD);
        float s = 0.0f;
#pragma unroll
        for (int j = 0; j < 16; ++j) {
            float4 a = *(const float4*)(p + 4 * j);
            float e;
            e = a.x * ls[4 * j + 0]; s = fmaf(e, e, s);
            e = a.y * ls[4 * j + 1]; s = fmaf(e, e, s);
            e = a.z * ls[4 * j + 2]; s = fmaf(e, e, s);
            e = a.w * ls[4 * j + 3]; s = fmaf(e, e, s);
        }
        if (t < 128) xn[rowl] = s; else yn[rowl] = s;
    }
    __syncthreads();

    // ---- MFMA: each wave computes a 64x64 quadrant via 4x4 16x16 tiles ----
    const int lane = t & 63;
    const int q    = lane >> 4;   // 0..3
    const int r16  = lane & 15;   // 0..15
    const int w    = t >> 6;      // wave 0..3
    const int row0 = (w >> 1) * 64;
    const int col0 = (w & 1) * 64;

    f32x4 acc[4][4];
#pragma unroll
    for (int mi = 0; mi < 4; ++mi)
#pragma unroll
        for (int ni = 0; ni < 4; ++ni)
#pragma unroll
            for (int r = 0; r < 4; ++r) acc[mi][ni][r] = 0.0f;

#pragma unroll
    for (int kc = 0; kc < 2; ++kc) {
        const int k0 = kc * 32 + q * 8;
        bf16x8 ah[4], al[4], bh[4], bl[4];
#pragma unroll
        for (int i = 0; i < 4; ++i) {
            ah[i] = *(const bf16x8*)&Ah[row0 + i * 16 + r16][k0];
            al[i] = *(const bf16x8*)&Al[row0 + i * 16 + r16][k0];
            bh[i] = *(const bf16x8*)&Bh[col0 + i * 16 + r16][k0];
            bl[i] = *(const bf16x8*)&Bl[col0 + i * 16 + r16][k0];
        }
#pragma unroll
        for (int mi = 0; mi < 4; ++mi) {
#pragma unroll
            for (int ni = 0; ni < 4; ++ni) {
                acc[mi][ni] = __builtin_amdgcn_mfma_f32_16x16x32_bf16(ah[mi], bh[ni], acc[mi][ni], 0, 0, 0);
                acc[mi][ni] = __builtin_amdgcn_mfma_f32_16x16x32_bf16(ah[mi], bl[ni], acc[mi][ni], 0, 0, 0);
                acc[mi][ni] = __builtin_amdgcn_mfma_f32_16x16x32_bf16(al[mi], bh[ni], acc[mi][ni], 0, 0, 0);
            }
        }
    }

    // ---- epilogue: d2 = max(xn+yn-2*cross,0); out = v * exp2(-0.5*log2e*d2) ----
    const float v  = softplus_f(raw_v[0]);
    const float ce = -0.5f * 1.4426950408889634f;

#pragma unroll
    for (int mi = 0; mi < 4; ++mi) {
#pragma unroll
        for (int r = 0; r < 4; ++r) {
            const int lrow = row0 + mi * 16 + q * 4 + r;
            const float xr = xn[lrow];
            float* orow = out + (size_t)(bm * BM + lrow) * MM + bn * BN;
#pragma unroll
            for (int ni = 0; ni < 4; ++ni) {
                const int lcol = col0 + ni * 16 + r16;
                float d2 = fmaxf(xr + yn[lcol] - 2.0f * acc[mi][ni][r], 0.0f);
                orow[lcol] = v * exp2f(ce * d2);
            }
        }
    }
}

extern "C" void kernel_launch(void* const* d_in, const int* in_sizes, int n_in,
                              void* d_out, int out_size, void* d_ws, size_t ws_size,
                              hipStream_t stream) {
    const float* X     = (const float*)d_in[0];
    const float* X2    = (const float*)d_in[1];
    const float* raw_l = (const float*)d_in[2];
    const float* raw_v = (const float*)d_in[3];
    float* out = (float*)d_out;

    dim3 grid(MM / BN, NN / BM);  // (64, 64)
    dim3 block(256);
    rbf_mfma_kernel<<<grid, block, 0, stream>>>(X, X2, raw_l, raw_v, out);
}